// Round 1
// baseline (626.063 us; speedup 1.0000x reference)
//
#include <hip/hip_runtime.h>
#include <hip/hip_fp16.h>
#include <math.h>

typedef _Float16 half8  __attribute__((ext_vector_type(8)));
typedef _Float16 half4v __attribute__((ext_vector_type(4)));
typedef float    floatx4 __attribute__((ext_vector_type(4)));

#define NB   4
#define LL   8192
#define FF   1024
#define HH   16
#define DD   64
#define MTOT 32768
#define KK   1024
#define NN   1024
#define ZSCALE 65536.0f

__device__ __forceinline__ void gload_lds16(const void* g, void* l) {
  __builtin_amdgcn_global_load_lds(
      (const __attribute__((address_space(1))) void*)g,
      (__attribute__((address_space(3))) void*)l, 16, 0, 0);
}

__device__ __forceinline__ float phi_act(float x) {
  // elu(x)+1 : x>0 -> x+1 ; x<=0 -> exp(x)
  return x > 0.f ? x + 1.f : __expf(x);
}

// ---------- elementwise f32 -> f16 ----------
__global__ void k_cvt(const float* __restrict__ src, _Float16* __restrict__ dst, int n4) {
  int stride = gridDim.x * blockDim.x;
  for (int i = blockIdx.x * blockDim.x + threadIdx.x; i < n4; i += stride) {
    float4 v = reinterpret_cast<const float4*>(src)[i];
    half4v h;
    h[0] = (_Float16)v.x; h[1] = (_Float16)v.y; h[2] = (_Float16)v.z; h[3] = (_Float16)v.w;
    reinterpret_cast<half4v*>(dst)[i] = h;
  }
}

// ---------- transpose+convert three 1024x1024 weights: W[f][n] -> WT16[n][f] ----------
__global__ void k_cvt_t(const float* __restrict__ W0, const float* __restrict__ W1,
                        const float* __restrict__ W2,
                        _Float16* __restrict__ T0, _Float16* __restrict__ T1,
                        _Float16* __restrict__ T2) {
  __shared__ float tile[32][33];
  int bid = blockIdx.x;
  int w = bid >> 10, rem = bid & 1023;
  int ti = rem >> 5, tj = rem & 31;
  const float* src = (w == 0) ? W0 : (w == 1) ? W1 : W2;
  _Float16*    dst = (w == 0) ? T0 : (w == 1) ? T1 : T2;
  int t = threadIdx.x;
  int r = t >> 3, c4 = (t & 7) << 2;
  float4 v = *reinterpret_cast<const float4*>(&src[(size_t)(ti * 32 + r) * FF + tj * 32 + c4]);
  tile[r][c4 + 0] = v.x; tile[r][c4 + 1] = v.y; tile[r][c4 + 2] = v.z; tile[r][c4 + 3] = v.w;
  __syncthreads();
  half4v h;
  h[0] = (_Float16)tile[c4 + 0][r];
  h[1] = (_Float16)tile[c4 + 1][r];
  h[2] = (_Float16)tile[c4 + 2][r];
  h[3] = (_Float16)tile[c4 + 3][r];
  *reinterpret_cast<half4v*>(&dst[(size_t)(tj * 32 + r) * FF + ti * 32 + c4]) = h;
}

// ---------- main 128x128 GEMM, K=N=1024, A[M,K] f16 row-major, BT[N,K] f16 row-major ----------
// MODE 0: store f16 C[row*NN+col] (optionally PHI)       (used for qp)
// MODE 1: store f16 transposed  CT[b][1024][LL]          (used for kpT / vT)
// MODE 2: store f32 C*outScale, BT indexed per-b         (final output)
template<int MODE, bool PHI>
__global__ __launch_bounds__(256)
void k_gemm(const _Float16* __restrict__ A, const _Float16* __restrict__ BT,
            void* __restrict__ Cptr, float outScale) {
  __shared__ _Float16 As[128 * 32];
  __shared__ _Float16 Bs[128 * 32];
  const int tid  = threadIdx.x;
  const int lane = tid & 63;
  const int w    = tid >> 6;
  const int wr   = w >> 1, wc = w & 1;
  const int tn = blockIdx.x & 7;
  const int tm = blockIdx.x >> 3;
  const int i0 = tm * 128, j0 = tn * 128;
  const int lr = lane & 15, lh = lane >> 4;

  const _Float16* BTb = BT;
  if constexpr (MODE == 2) BTb = BT + ((size_t)(i0 >> 13)) * ((size_t)NN * KK);

  floatx4 acc[4][4];
  #pragma unroll
  for (int m = 0; m < 4; ++m)
    #pragma unroll
    for (int n = 0; n < 4; ++n)
      #pragma unroll
      for (int r = 0; r < 4; ++r) acc[m][n][r] = 0.f;

  const int rA = w * 16 + (lane >> 2);   // staging row within 64-row group
  const int kb = (lane & 3) * 8;         // staging k-offset (elements)

  for (int kt = 0; kt < KK; kt += 32) {
    gload_lds16(A   + (size_t)(i0 + rA     ) * KK + kt + kb, As + (w * 16     ) * 32);
    gload_lds16(A   + (size_t)(i0 + rA + 64) * KK + kt + kb, As + (w * 16 + 64) * 32);
    gload_lds16(BTb + (size_t)(j0 + rA     ) * KK + kt + kb, Bs + (w * 16     ) * 32);
    gload_lds16(BTb + (size_t)(j0 + rA + 64) * KK + kt + kb, Bs + (w * 16 + 64) * 32);
    __syncthreads();
    half8 af[4], bf[4];
    #pragma unroll
    for (int m = 0; m < 4; ++m) af[m] = *(const half8*)&As[(wr * 64 + m * 16 + lr) * 32 + lh * 8];
    #pragma unroll
    for (int n = 0; n < 4; ++n) bf[n] = *(const half8*)&Bs[(wc * 64 + n * 16 + lr) * 32 + lh * 8];
    #pragma unroll
    for (int m = 0; m < 4; ++m)
      #pragma unroll
      for (int n = 0; n < 4; ++n)
        acc[m][n] = __builtin_amdgcn_mfma_f32_16x16x32_f16(af[m], bf[n], acc[m][n], 0, 0, 0);
    __syncthreads();
  }

  if constexpr (MODE == 0) {
    _Float16* C = (_Float16*)Cptr;
    #pragma unroll
    for (int m = 0; m < 4; ++m)
      #pragma unroll
      for (int n = 0; n < 4; ++n) {
        int col = j0 + wc * 64 + n * 16 + lr;
        #pragma unroll
        for (int r = 0; r < 4; ++r) {
          int row = i0 + wr * 64 + m * 16 + lh * 4 + r;
          float v = acc[m][n][r];
          if constexpr (PHI) v = phi_act(v);
          C[(size_t)row * NN + col] = (_Float16)v;
        }
      }
  } else if constexpr (MODE == 2) {
    float* C = (float*)Cptr;
    #pragma unroll
    for (int m = 0; m < 4; ++m)
      #pragma unroll
      for (int n = 0; n < 4; ++n) {
        int col = j0 + wc * 64 + n * 16 + lr;
        #pragma unroll
        for (int r = 0; r < 4; ++r) {
          int row = i0 + wr * 64 + m * 16 + lh * 4 + r;
          C[(size_t)row * NN + col] = acc[m][n][r] * outScale;
        }
      }
  } else {
    // transposed store via LDS: Tb[col_local][row_local]
    __shared__ _Float16 Tb[128 * 136];
    #pragma unroll
    for (int m = 0; m < 4; ++m)
      #pragma unroll
      for (int n = 0; n < 4; ++n) {
        int coll = wc * 64 + n * 16 + lr;
        #pragma unroll
        for (int r = 0; r < 4; ++r) {
          int rowl = wr * 64 + m * 16 + lh * 4 + r;
          float v = acc[m][n][r];
          if constexpr (PHI) v = phi_act(v);
          Tb[coll * 136 + rowl] = (_Float16)v;
        }
      }
    __syncthreads();
    _Float16* C = (_Float16*)Cptr;
    const int bb = i0 >> 13;       // batch of this row tile (8192 rows per batch)
    const int l0 = i0 & 8191;
    const int cc = tid & 15;       // 16 x 8-element chunks per 128-row segment
    const int h0 = tid >> 4;
    #pragma unroll
    for (int i = 0; i < 8; ++i) {
      int hdl = h0 + i * 16;
      half8 v8 = *(const half8*)&Tb[hdl * 136 + cc * 8];
      *(half8*)&C[((size_t)bb * 1024 + j0 + hdl) * LL + l0 + cc * 8] = v8;
    }
  }
}

// ---------- ksum[b,h,d] = sum_l phi(k): row sums of kpT ----------
__global__ void k_ksum(const _Float16* __restrict__ kpT, float* __restrict__ ksum) {
  int w = threadIdx.x >> 6, lane = threadIdx.x & 63;
  int row = blockIdx.x * 4 + w;   // 0..4095  (= b*1024 + h*64 + d)
  const _Float16* p = kpT + (size_t)row * LL;
  float s = 0.f;
  for (int j = 0; j < 16; ++j) {
    half8 v = *(const half8*)&p[j * 512 + lane * 8];
    #pragma unroll
    for (int e = 0; e < 8; ++e) s += (float)v[e];
  }
  #pragma unroll
  for (int off = 1; off < 64; off <<= 1) s += __shfl_xor(s, off);
  if (lane == 0) ksum[row] = s;
}

// ---------- kv partials: per (b,h,chunk) wave computes 64x64 = kp^T(chunk) * v(chunk) ----------
__global__ __launch_bounds__(64)
void k_stageB(const _Float16* __restrict__ kpT, const _Float16* __restrict__ vT,
              float* __restrict__ kvpart) {
  __shared__ _Float16 Ak[64 * 72];
  __shared__ _Float16 Bv[64 * 72];
  const int bid = blockIdx.x;           // bh*16 + chunk
  const int bh = bid >> 4, cc = bid & 15;
  const int lane = threadIdx.x;
  const int lr = lane & 15, lh = lane >> 4;
  const _Float16* Ab = kpT + (size_t)bh * 64 * LL + cc * 512;
  const _Float16* Bb = vT  + (size_t)bh * 64 * LL + cc * 512;

  floatx4 acc[4][4];
  #pragma unroll
  for (int m = 0; m < 4; ++m)
    #pragma unroll
    for (int n = 0; n < 4; ++n)
      #pragma unroll
      for (int r = 0; r < 4; ++r) acc[m][n][r] = 0.f;

  for (int kt = 0; kt < 512; kt += 64) {
    __syncthreads();
    #pragma unroll
    for (int j = 0; j < 8; ++j) {
      int chunk = lane + 64 * j;
      int rr = chunk >> 3;
      int off = (chunk & 7) * 8;
      *(half8*)&Ak[rr * 72 + off] = *(const half8*)&Ab[(size_t)rr * LL + kt + off];
      *(half8*)&Bv[rr * 72 + off] = *(const half8*)&Bb[(size_t)rr * LL + kt + off];
    }
    __syncthreads();
    #pragma unroll
    for (int ks = 0; ks < 2; ++ks) {
      half8 af[4], bf[4];
      #pragma unroll
      for (int m = 0; m < 4; ++m) af[m] = *(const half8*)&Ak[(m * 16 + lr) * 72 + ks * 32 + lh * 8];
      #pragma unroll
      for (int n = 0; n < 4; ++n) bf[n] = *(const half8*)&Bv[(n * 16 + lr) * 72 + ks * 32 + lh * 8];
      #pragma unroll
      for (int m = 0; m < 4; ++m)
        #pragma unroll
        for (int n = 0; n < 4; ++n)
          acc[m][n] = __builtin_amdgcn_mfma_f32_16x16x32_f16(af[m], bf[n], acc[m][n], 0, 0, 0);
    }
  }
  float* op = kvpart + (size_t)bid * 4096;
  #pragma unroll
  for (int m = 0; m < 4; ++m)
    #pragma unroll
    for (int n = 0; n < 4; ++n)
      #pragma unroll
      for (int r = 0; r < 4; ++r)
        op[(m * 16 + lh * 4 + r) * 64 + n * 16 + lr] = acc[m][n][r];
}

// ---------- reduce kv partials over 16 chunks ----------
__global__ void k_reduce_kv(const float* __restrict__ kvpart, float* __restrict__ kv) {
  int gid = blockIdx.x * 256 + threadIdx.x;  // 262144 outputs
  int bh = gid >> 12, i = gid & 4095;
  float s = 0.f;
  for (int c = 0; c < 16; ++c) s += kvpart[((size_t)bh * 16 + c) * 4096 + i];
  kv[gid] = s;
}

// ---------- z = ZSCALE / (phi(q).ksum + eps); qp *= z in place ----------
__global__ void k_zscale(_Float16* __restrict__ qp, const float* __restrict__ ksum) {
  int w = threadIdx.x >> 6, lane = threadIdx.x & 63;
  int row = blockIdx.x * 4 + w;              // 0..32767
  int b = row >> 13;
  int h = lane >> 2;
  _Float16* p = qp + (size_t)row * 1024 + lane * 16;
  half8 v0 = *(half8*)&p[0];
  half8 v1 = *(half8*)&p[8];
  const float* ks = ksum + ((size_t)b * 16 + h) * 64 + (lane & 3) * 16;
  float dot = 0.f;
  #pragma unroll
  for (int e = 0; e < 8; ++e) dot += (float)v0[e] * ks[e];
  #pragma unroll
  for (int e = 0; e < 8; ++e) dot += (float)v1[e] * ks[8 + e];
  dot += __shfl_xor(dot, 1);
  dot += __shfl_xor(dot, 2);
  float zf = ZSCALE / (dot + 1e-6f);
  #pragma unroll
  for (int e = 0; e < 8; ++e) v0[e] = (_Float16)((float)v0[e] * zf);
  #pragma unroll
  for (int e = 0; e < 8; ++e) v1[e] = (_Float16)((float)v1[e] * zf);
  *(half8*)&p[0] = v0;
  *(half8*)&p[8] = v1;
}

// ---------- MT[b][f][h*64+d] = sum_e kv[b,h,d,e] * Wo[h,e,f] ----------
__global__ __launch_bounds__(256)
void k_mker(const float* __restrict__ kv, const _Float16* __restrict__ Wo16,
            _Float16* __restrict__ MT) {
  __shared__ float kvs[4096];
  int bid = blockIdx.x;                 // b*64 + h*4 + fc
  int fc = bid & 3, h = (bid >> 2) & 15, b = bid >> 6;
  const float* kvp = kv + ((size_t)b * 16 + h) * 4096;
  for (int i = threadIdx.x; i < 4096; i += 256) kvs[i] = kvp[i];
  __syncthreads();
  int f = fc * 256 + threadIdx.x;
  float acc[64];
  #pragma unroll
  for (int d = 0; d < 64; ++d) acc[d] = 0.f;
  for (int e = 0; e < 64; ++e) {
    float wv = (float)Wo16[(size_t)(h * 64 + e) * 1024 + f];
    #pragma unroll
    for (int d = 0; d < 64; ++d) acc[d] = fmaf(kvs[d * 64 + e], wv, acc[d]);
  }
  _Float16* op = MT + ((size_t)b * 1024 + f) * 1024 + h * 64;
  #pragma unroll
  for (int g = 0; g < 8; ++g) {
    half8 o;
    #pragma unroll
    for (int j = 0; j < 8; ++j) o[j] = (_Float16)acc[g * 8 + j];
    *(half8*)&op[g * 8] = o;
  }
}

extern "C" void kernel_launch(void* const* d_in, const int* in_sizes, int n_in,
                              void* d_out, int out_size, void* d_ws, size_t ws_size,
                              hipStream_t stream) {
  (void)in_sizes; (void)n_in; (void)out_size; (void)ws_size;
  const float* xq  = (const float*)d_in[0];
  const float* xkv = (const float*)d_in[1];
  const float* Wq  = (const float*)d_in[2];
  const float* Wk  = (const float*)d_in[3];
  const float* Wv  = (const float*)d_in[4];
  const float* Wo  = (const float*)d_in[5];

  // workspace layout (236 MB total)
  char* ws = (char*)d_ws;
  _Float16* qp16 = (_Float16*)(ws + 0);           // 67,108,864  [32768][1024]
  _Float16* kpT  = (_Float16*)(ws + 67108864);    // 67,108,864  [4][1024][8192]
  _Float16* vT   = (_Float16*)(ws + 134217728);   // 67,108,864  [4][1024][8192]
  _Float16* WqT  = (_Float16*)(ws + 201326592);   // 2,097,152   [1024][1024]
  _Float16* WkT  = (_Float16*)(ws + 203423744);   // 2,097,152
  _Float16* WvT  = (_Float16*)(ws + 205520896);   // 2,097,152
  _Float16* Wo16 = (_Float16*)(ws + 207618048);   // 2,097,152   [1024][1024] row-major
  float*    ksum = (float*)(ws + 209715200);      // 16,384      [4][16][64]
  float*    kv   = (float*)(ws + 209731584);      // 1,048,576   [4][16][64][64]
  float*    kvpart = (float*)(ws + 210780160);    // 16,777,216  [64][16][64][64]
  _Float16* MT   = (_Float16*)(ws + 227557376);   // 8,388,608   [4][1024][1024]

  // converted f16 inputs live in d_out (dead before the final GEMM writes it)
  _Float16* Xq16  = (_Float16*)d_out;             // 33,554,432 elems
  _Float16* Xkv16 = Xq16 + 33554432;              // 33,554,432 elems

  // 1) convert inputs + Wo, transpose-convert Wq/Wk/Wv
  k_cvt<<<2048, 256, 0, stream>>>(xq,  Xq16,  8388608);
  k_cvt<<<2048, 256, 0, stream>>>(xkv, Xkv16, 8388608);
  k_cvt<<<512,  256, 0, stream>>>(Wo,  Wo16,  262144);
  k_cvt_t<<<3072, 256, 0, stream>>>(Wq, Wk, Wv, WqT, WkT, WvT);

  // 2) projections (128x128 tiles: 256 x 8 = 2048 blocks)
  k_gemm<0, true ><<<2048, 256, 0, stream>>>(Xq16,  WqT, qp16, 1.0f);
  k_gemm<1, true ><<<2048, 256, 0, stream>>>(Xkv16, WkT, kpT,  1.0f);
  k_gemm<1, false><<<2048, 256, 0, stream>>>(Xkv16, WvT, vT,   1.0f);

  // 3) reductions over L
  k_ksum<<<1024, 256, 0, stream>>>(kpT, ksum);
  k_stageB<<<1024, 64, 0, stream>>>(kpT, vT, kvpart);
  k_reduce_kv<<<1024, 256, 0, stream>>>(kvpart, kv);

  // 4) normalizer folded into qp (scaled by 2^16 for f16 range)
  k_zscale<<<8192, 256, 0, stream>>>(qp16, ksum);

  // 5) MT[b] = (kv . Wo)^T ; final GEMM -> d_out (f32), undo 2^16 scale
  k_mker<<<256, 256, 0, stream>>>(kv, Wo16, MT);
  k_gemm<2, false><<<2048, 256, 0, stream>>>(qp16, MT, d_out, 1.0f / ZSCALE);
}

// Round 2
// 520.009 us; speedup vs baseline: 1.2039x; 1.2039x over previous
//
#include <hip/hip_runtime.h>
#include <hip/hip_fp16.h>
#include <math.h>

typedef _Float16 half8  __attribute__((ext_vector_type(8)));
typedef _Float16 half4v __attribute__((ext_vector_type(4)));
typedef float    floatx4 __attribute__((ext_vector_type(4)));

#define NB   4
#define LL   8192
#define FF   1024
#define HH   16
#define DD   64
#define MTOT 32768
#define KK   1024
#define NN   1024
#define ZSCALE 65536.0f

__device__ __forceinline__ void gload_lds16(const void* g, void* l) {
  __builtin_amdgcn_global_load_lds(
      (const __attribute__((address_space(1))) void*)g,
      (__attribute__((address_space(3))) void*)l, 16, 0, 0);
}

__device__ __forceinline__ float phi_act(float x) {
  return x > 0.f ? x + 1.f : __expf(x);
}

// ---------- elementwise f32 -> f16 ----------
__global__ void k_cvt(const float* __restrict__ src, _Float16* __restrict__ dst, int n4) {
  int stride = gridDim.x * blockDim.x;
  for (int i = blockIdx.x * blockDim.x + threadIdx.x; i < n4; i += stride) {
    float4 v = reinterpret_cast<const float4*>(src)[i];
    half4v h;
    h[0] = (_Float16)v.x; h[1] = (_Float16)v.y; h[2] = (_Float16)v.z; h[3] = (_Float16)v.w;
    reinterpret_cast<half4v*>(dst)[i] = h;
  }
}

// ---------- transpose+convert three 1024x1024 weights: W[f][n] -> WT16[n][f] ----------
__global__ void k_cvt_t(const float* __restrict__ W0, const float* __restrict__ W1,
                        const float* __restrict__ W2,
                        _Float16* __restrict__ T0, _Float16* __restrict__ T1,
                        _Float16* __restrict__ T2) {
  __shared__ float tile[32][33];
  int bid = blockIdx.x;
  int w = bid >> 10, rem = bid & 1023;
  int ti = rem >> 5, tj = rem & 31;
  const float* src = (w == 0) ? W0 : (w == 1) ? W1 : W2;
  _Float16*    dst = (w == 0) ? T0 : (w == 1) ? T1 : T2;
  int t = threadIdx.x;
  int r = t >> 3, c4 = (t & 7) << 2;
  float4 v = *reinterpret_cast<const float4*>(&src[(size_t)(ti * 32 + r) * FF + tj * 32 + c4]);
  tile[r][c4 + 0] = v.x; tile[r][c4 + 1] = v.y; tile[r][c4 + 2] = v.z; tile[r][c4 + 3] = v.w;
  __syncthreads();
  half4v h;
  h[0] = (_Float16)tile[c4 + 0][r];
  h[1] = (_Float16)tile[c4 + 1][r];
  h[2] = (_Float16)tile[c4 + 2][r];
  h[3] = (_Float16)tile[c4 + 3][r];
  *reinterpret_cast<half4v*>(&dst[(size_t)(tj * 32 + r) * FF + ti * 32 + c4]) = h;
}

// ============ 256x256-tile 8-phase GEMM (BK=64, 8 waves 2x4) ============
// A[M,1024] f16 row-major, BT[N(=1024),1024] f16 row-major.
// LDS: A planes [2 buf][2 kk][256 rows][32 k] f16 (16KB each) at smem+0,
//      B planes same at smem+32768 elems.  Total 128 KiB.
// Swizzle (involution): byte ^= ((byte>>7)&3)<<4  (row bits 1-2 -> byte bits 4-5).
// Staged via global_load_lds with LINEAR lds dest + pre-swizzled global source.

// stage one 16KB plane half-tile: 2 x global_load_lds_dwordx4 per thread
__device__ __forceinline__ void stage_plane(const _Float16* __restrict__ G, int row0,
                                            int col0, _Float16* plane, int tid) {
  #pragma unroll
  for (int is = 0; is < 2; ++is) {
    int lin = is * 8192 + tid * 16;                    // byte offset in plane
    int swz = lin ^ (((lin >> 7) & 3) << 4);
    int row = swz >> 6, kcb = swz & 63;
    gload_lds16(G + (size_t)(row0 + row) * 1024 + col0 + (kcb >> 1),
                (char*)plane + lin);
  }
}

template<int BUF, int KKH, int MH, bool LOADB>
__device__ __forceinline__ void do_phase(const _Float16* smem, floatx4 (&acc)[8][4],
                                         half8 (&bfr)[4], int wr, int wc, int lr, int khix) {
  asm volatile("s_waitcnt vmcnt(6)" ::: "memory");
  __builtin_amdgcn_sched_barrier(0);
  __builtin_amdgcn_s_barrier();
  __builtin_amdgcn_sched_barrier(0);
  const _Float16* pa = smem + (BUF * 2 + KKH) * 8192 + (wr * 128 + MH * 64 + lr) * 32 + khix * 8;
  const _Float16* pb = smem + 32768 + (BUF * 2 + KKH) * 8192 + (wc * 64 + lr) * 32 + khix * 8;
  half8 af[4];
  #pragma unroll
  for (int mm = 0; mm < 4; ++mm) af[mm] = *(const half8*)(pa + mm * 16 * 32);
  if constexpr (LOADB) {
    #pragma unroll
    for (int n = 0; n < 4; ++n) bfr[n] = *(const half8*)(pb + n * 16 * 32);
  }
  __builtin_amdgcn_s_setprio(1);
  #pragma unroll
  for (int mm = 0; mm < 4; ++mm)
    #pragma unroll
    for (int n = 0; n < 4; ++n)
      acc[MH * 4 + mm][n] =
          __builtin_amdgcn_mfma_f32_16x16x32_f16(af[mm], bfr[n], acc[MH * 4 + mm][n], 0, 0, 0);
  __builtin_amdgcn_s_setprio(0);
}

// MODE 0: f16 C[row*1024+col] (opt PHI)   MODE 1: f16 transposed CT[b][1024][8192]
// MODE 2: f32 C*outScale, BT indexed per-batch
template<int MODE, bool PHI>
__global__ __launch_bounds__(512, 2)
void k_gemm(const _Float16* __restrict__ A, const _Float16* __restrict__ BT,
            void* __restrict__ Cptr, float outScale) {
  __shared__ __align__(16) _Float16 smem[65536];   // 128 KiB
  const int tid  = threadIdx.x;
  const int lane = tid & 63;
  const int wid  = tid >> 6;
  const int wr = wid >> 2, wc = wid & 3;
  const int lr = lane & 15, lh = lane >> 4;
  const int khix = lh ^ ((lr >> 1) & 3);           // swizzled k-quad for frag reads

  // XCD-chunked block swizzle: 512 blocks, 64 contiguous tiles per XCD
  const int tile = (blockIdx.x & 7) * 64 + (blockIdx.x >> 3);
  const int tm = tile >> 2, tn = tile & 3;
  const int i0 = tm * 256, j0 = tn * 256;

  const _Float16* Ab = A;
  const _Float16* Bb = (MODE == 2) ? BT + ((size_t)(i0 >> 13)) * ((size_t)NN * KK) : BT;

  floatx4 acc[8][4];
  #pragma unroll
  for (int m = 0; m < 8; ++m)
    #pragma unroll
    for (int n = 0; n < 4; ++n)
      #pragma unroll
      for (int r = 0; r < 4; ++r) acc[m][n][r] = 0.f;

  _Float16* sm = (_Float16*)smem;
  // prologue: stage K-tile 0 (A-k0, B-k0, A-k1, B-k1) into buf0
  stage_plane(Ab, i0, 0,  sm + 0,             tid);
  stage_plane(Bb, j0, 0,  sm + 32768,         tid);
  stage_plane(Ab, i0, 32, sm + 8192,          tid);
  stage_plane(Bb, j0, 32, sm + 32768 + 8192,  tid);

  half8 bfr[4];
  #pragma unroll 1
  for (int t2 = 0; t2 < 8; ++t2) {
    const int ka = ((t2 * 2 + 1) & 15) * 64;   // k-col of next tile (even->odd)
    const int kb = ((t2 * 2 + 2) & 15) * 64;   // k-col of tile after (odd->even, wraps)
    // ---- tile t0 (buf0), stage into buf1 ----
    stage_plane(Ab, i0, ka +  0, sm + 16384,                 tid);
    do_phase<0,0,0,true >(sm, acc, bfr, wr, wc, lr, khix);
    stage_plane(Bb, j0, ka +  0, sm + 32768 + 16384,         tid);
    do_phase<0,0,1,false>(sm, acc, bfr, wr, wc, lr, khix);
    stage_plane(Ab, i0, ka + 32, sm + 16384 + 8192,          tid);
    do_phase<0,1,0,true >(sm, acc, bfr, wr, wc, lr, khix);
    stage_plane(Bb, j0, ka + 32, sm + 32768 + 16384 + 8192,  tid);
    do_phase<0,1,1,false>(sm, acc, bfr, wr, wc, lr, khix);
    // ---- tile t1 (buf1), stage into buf0 ----
    stage_plane(Ab, i0, kb +  0, sm + 0,                     tid);
    do_phase<1,0,0,true >(sm, acc, bfr, wr, wc, lr, khix);
    stage_plane(Bb, j0, kb +  0, sm + 32768,                 tid);
    do_phase<1,0,1,false>(sm, acc, bfr, wr, wc, lr, khix);
    stage_plane(Ab, i0, kb + 32, sm + 8192,                  tid);
    do_phase<1,1,0,true >(sm, acc, bfr, wr, wc, lr, khix);
    stage_plane(Bb, j0, kb + 32, sm + 32768 + 8192,          tid);
    do_phase<1,1,1,false>(sm, acc, bfr, wr, wc, lr, khix);
  }

  asm volatile("s_waitcnt vmcnt(0)" ::: "memory");
  __builtin_amdgcn_sched_barrier(0);
  __builtin_amdgcn_s_barrier();

  if constexpr (MODE == 0) {
    _Float16* C = (_Float16*)Cptr;
    #pragma unroll
    for (int m = 0; m < 8; ++m) {
      int row = i0 + wr * 128 + m * 16 + lh * 4;
      #pragma unroll
      for (int n = 0; n < 4; ++n) {
        int col = j0 + wc * 64 + n * 16 + lr;
        #pragma unroll
        for (int r = 0; r < 4; ++r) {
          float v = acc[m][n][r];
          if constexpr (PHI) v = phi_act(v);
          C[(size_t)(row + r) * NN + col] = (_Float16)v;
        }
      }
    }
  } else if constexpr (MODE == 2) {
    float* C = (float*)Cptr;
    #pragma unroll
    for (int m = 0; m < 8; ++m) {
      int row = i0 + wr * 128 + m * 16 + lh * 4;
      #pragma unroll
      for (int n = 0; n < 4; ++n) {
        int col = j0 + wc * 64 + n * 16 + lr;
        #pragma unroll
        for (int r = 0; r < 4; ++r)
          C[(size_t)(row + r) * NN + col] = acc[m][n][r] * outScale;
      }
    }
  } else {
    // transposed store via LDS (reuse smem = 256n x 256l f16 = 128KB exactly)
    // swizzle: byte ^= (n_loc&7)<<4  (involution: source bits 9-11, modified 4-6)
    #pragma unroll
    for (int m = 0; m < 8; ++m) {
      int l0l = wr * 128 + m * 16 + lh * 4;
      #pragma unroll
      for (int n = 0; n < 4; ++n) {
        int n_loc = wc * 64 + n * 16 + lr;
        int byte = (n_loc * 512 + l0l * 2) ^ ((n_loc & 7) << 4);
        half4v h;
        #pragma unroll
        for (int r = 0; r < 4; ++r) {
          float v = acc[m][n][r];
          if constexpr (PHI) v = phi_act(v);
          h[r] = (_Float16)v;
        }
        *(half4v*)((char*)sm + byte) = h;
      }
    }
    __syncthreads();
    _Float16* C = (_Float16*)Cptr;
    const int bb = i0 >> 13;
    const int l0 = i0 & 8191;
    #pragma unroll 1
    for (int pass = 0; pass < 16; ++pass) {
      int n_loc = pass * 16 + (tid >> 5);
      int lo = (tid & 31) * 16;                     // byte offset within 512B l-row
      int byte = (n_loc * 512 + lo) ^ ((n_loc & 7) << 4);
      half8 v = *(const half8*)((char*)sm + byte);
      *(half8*)&C[((size_t)bb * 1024 + j0 + n_loc) * LL + l0 + (lo >> 1)] = v;
    }
  }
}

// ---------- ksum[b,h,d] = sum_l phi(k): row sums of kpT ----------
__global__ void k_ksum(const _Float16* __restrict__ kpT, float* __restrict__ ksum) {
  int w = threadIdx.x >> 6, lane = threadIdx.x & 63;
  int row = blockIdx.x * 4 + w;
  const _Float16* p = kpT + (size_t)row * LL;
  float s = 0.f;
  for (int j = 0; j < 16; ++j) {
    half8 v = *(const half8*)&p[j * 512 + lane * 8];
    #pragma unroll
    for (int e = 0; e < 8; ++e) s += (float)v[e];
  }
  #pragma unroll
  for (int off = 1; off < 64; off <<= 1) s += __shfl_xor(s, off);
  if (lane == 0) ksum[row] = s;
}

// ---------- kv partials: per (b,h,chunk) wave computes 64x64 = kp^T(chunk) * v(chunk) ----------
__global__ __launch_bounds__(64)
void k_stageB(const _Float16* __restrict__ kpT, const _Float16* __restrict__ vT,
              float* __restrict__ kvpart) {
  __shared__ _Float16 Ak[64 * 72];
  __shared__ _Float16 Bv[64 * 72];
  const int bid = blockIdx.x;
  const int bh = bid >> 4, cc = bid & 15;
  const int lane = threadIdx.x;
  const int lr = lane & 15, lh = lane >> 4;
  const _Float16* Ab = kpT + (size_t)bh * 64 * LL + cc * 512;
  const _Float16* Bb = vT  + (size_t)bh * 64 * LL + cc * 512;

  floatx4 acc[4][4];
  #pragma unroll
  for (int m = 0; m < 4; ++m)
    #pragma unroll
    for (int n = 0; n < 4; ++n)
      #pragma unroll
      for (int r = 0; r < 4; ++r) acc[m][n][r] = 0.f;

  for (int kt = 0; kt < 512; kt += 64) {
    __syncthreads();
    #pragma unroll
    for (int j = 0; j < 8; ++j) {
      int chunk = lane + 64 * j;
      int rr = chunk >> 3;
      int off = (chunk & 7) * 8;
      *(half8*)&Ak[rr * 72 + off] = *(const half8*)&Ab[(size_t)rr * LL + kt + off];
      *(half8*)&Bv[rr * 72 + off] = *(const half8*)&Bb[(size_t)rr * LL + kt + off];
    }
    __syncthreads();
    #pragma unroll
    for (int ks = 0; ks < 2; ++ks) {
      half8 af[4], bf[4];
      #pragma unroll
      for (int m = 0; m < 4; ++m) af[m] = *(const half8*)&Ak[(m * 16 + lr) * 72 + ks * 32 + lh * 8];
      #pragma unroll
      for (int n = 0; n < 4; ++n) bf[n] = *(const half8*)&Bv[(n * 16 + lr) * 72 + ks * 32 + lh * 8];
      #pragma unroll
      for (int m = 0; m < 4; ++m)
        #pragma unroll
        for (int n = 0; n < 4; ++n)
          acc[m][n] = __builtin_amdgcn_mfma_f32_16x16x32_f16(af[m], bf[n], acc[m][n], 0, 0, 0);
    }
  }
  float* op = kvpart + (size_t)bid * 4096;
  #pragma unroll
  for (int m = 0; m < 4; ++m)
    #pragma unroll
    for (int n = 0; n < 4; ++n)
      #pragma unroll
      for (int r = 0; r < 4; ++r)
        op[(m * 16 + lh * 4 + r) * 64 + n * 16 + lr] = acc[m][n][r];
}

// ---------- reduce kv partials over 16 chunks ----------
__global__ void k_reduce_kv(const float* __restrict__ kvpart, float* __restrict__ kv) {
  int gid = blockIdx.x * 256 + threadIdx.x;
  int bh = gid >> 12, i = gid & 4095;
  float s = 0.f;
  for (int c = 0; c < 16; ++c) s += kvpart[((size_t)bh * 16 + c) * 4096 + i];
  kv[gid] = s;
}

// ---------- z = ZSCALE / (phi(q).ksum + eps); qp *= z in place ----------
__global__ void k_zscale(_Float16* __restrict__ qp, const float* __restrict__ ksum) {
  int w = threadIdx.x >> 6, lane = threadIdx.x & 63;
  int row = blockIdx.x * 4 + w;
  int b = row >> 13;
  int h = lane >> 2;
  _Float16* p = qp + (size_t)row * 1024 + lane * 16;
  half8 v0 = *(half8*)&p[0];
  half8 v1 = *(half8*)&p[8];
  const float* ks = ksum + ((size_t)b * 16 + h) * 64 + (lane & 3) * 16;
  float dot = 0.f;
  #pragma unroll
  for (int e = 0; e < 8; ++e) dot += (float)v0[e] * ks[e];
  #pragma unroll
  for (int e = 0; e < 8; ++e) dot += (float)v1[e] * ks[8 + e];
  dot += __shfl_xor(dot, 1);
  dot += __shfl_xor(dot, 2);
  float zf = ZSCALE / (dot + 1e-6f);
  #pragma unroll
  for (int e = 0; e < 8; ++e) v0[e] = (_Float16)((float)v0[e] * zf);
  #pragma unroll
  for (int e = 0; e < 8; ++e) v1[e] = (_Float16)((float)v1[e] * zf);
  *(half8*)&p[0] = v0;
  *(half8*)&p[8] = v1;
}

// ---------- MT[b][f][h*64+d] = sum_e kv[b,h,d,e] * Wo[h,e,f] ----------
__global__ __launch_bounds__(256)
void k_mker(const float* __restrict__ kv, const _Float16* __restrict__ Wo16,
            _Float16* __restrict__ MT) {
  __shared__ float kvs[4096];
  int bid = blockIdx.x;
  int fc = bid & 3, h = (bid >> 2) & 15, b = bid >> 6;
  const float* kvp = kv + ((size_t)b * 16 + h) * 4096;
  for (int i = threadIdx.x; i < 4096; i += 256) kvs[i] = kvp[i];
  __syncthreads();
  int f = fc * 256 + threadIdx.x;
  float acc[64];
  #pragma unroll
  for (int d = 0; d < 64; ++d) acc[d] = 0.f;
  for (int e = 0; e < 64; ++e) {
    float wv = (float)Wo16[(size_t)(h * 64 + e) * 1024 + f];
    #pragma unroll
    for (int d = 0; d < 64; ++d) acc[d] = fmaf(kvs[d * 64 + e], wv, acc[d]);
  }
  _Float16* op = MT + ((size_t)b * 1024 + f) * 1024 + h * 64;
  #pragma unroll
  for (int g = 0; g < 8; ++g) {
    half8 o;
    #pragma unroll
    for (int j = 0; j < 8; ++j) o[j] = (_Float16)acc[g * 8 + j];
    *(half8*)&op[g * 8] = o;
  }
}

extern "C" void kernel_launch(void* const* d_in, const int* in_sizes, int n_in,
                              void* d_out, int out_size, void* d_ws, size_t ws_size,
                              hipStream_t stream) {
  (void)in_sizes; (void)n_in; (void)out_size; (void)ws_size;
  const float* xq  = (const float*)d_in[0];
  const float* xkv = (const float*)d_in[1];
  const float* Wq  = (const float*)d_in[2];
  const float* Wk  = (const float*)d_in[3];
  const float* Wv  = (const float*)d_in[4];
  const float* Wo  = (const float*)d_in[5];

  char* ws = (char*)d_ws;
  _Float16* qp16 = (_Float16*)(ws + 0);           // [32768][1024]
  _Float16* kpT  = (_Float16*)(ws + 67108864);    // [4][1024][8192]
  _Float16* vT   = (_Float16*)(ws + 134217728);   // [4][1024][8192]
  _Float16* WqT  = (_Float16*)(ws + 201326592);
  _Float16* WkT  = (_Float16*)(ws + 203423744);
  _Float16* WvT  = (_Float16*)(ws + 205520896);
  _Float16* Wo16 = (_Float16*)(ws + 207618048);
  float*    ksum = (float*)(ws + 209715200);
  float*    kv   = (float*)(ws + 209731584);
  float*    kvpart = (float*)(ws + 210780160);
  _Float16* MT   = (_Float16*)(ws + 227557376);   // [4][1024][1024]

  _Float16* Xq16  = (_Float16*)d_out;
  _Float16* Xkv16 = Xq16 + 33554432;

  k_cvt<<<2048, 256, 0, stream>>>(xq,  Xq16,  8388608);
  k_cvt<<<2048, 256, 0, stream>>>(xkv, Xkv16, 8388608);
  k_cvt<<<512,  256, 0, stream>>>(Wo,  Wo16,  262144);
  k_cvt_t<<<3072, 256, 0, stream>>>(Wq, Wk, Wv, WqT, WkT, WvT);

  // projections: 256x256 tiles -> 128 x 4 = 512 blocks of 512 threads
  k_gemm<0, true ><<<512, 512, 0, stream>>>(Xq16,  WqT, qp16, 1.0f);
  k_gemm<1, true ><<<512, 512, 0, stream>>>(Xkv16, WkT, kpT,  1.0f);
  k_gemm<1, false><<<512, 512, 0, stream>>>(Xkv16, WvT, vT,   1.0f);

  k_ksum<<<1024, 256, 0, stream>>>(kpT, ksum);
  k_stageB<<<1024, 64, 0, stream>>>(kpT, vT, kvpart);
  k_reduce_kv<<<1024, 256, 0, stream>>>(kvpart, kv);

  k_zscale<<<8192, 256, 0, stream>>>(qp16, ksum);

  k_mker<<<256, 256, 0, stream>>>(kv, Wo16, MT);
  k_gemm<2, false><<<512, 512, 0, stream>>>(qp16, MT, d_out, 1.0f / ZSCALE);
}

// Round 4
// 512.951 us; speedup vs baseline: 1.2205x; 1.0138x over previous
//
#include <hip/hip_runtime.h>
#include <hip/hip_fp16.h>
#include <math.h>

typedef _Float16 half8  __attribute__((ext_vector_type(8)));
typedef _Float16 half4v __attribute__((ext_vector_type(4)));
typedef float    floatx4 __attribute__((ext_vector_type(4)));

#define NB   4
#define LL   8192
#define FF   1024
#define HH   16
#define DD   64
#define MTOT 32768
#define KK   1024
#define NN   1024
#define ZSCALE 65536.0f

__device__ __forceinline__ void gload_lds16(const void* g, void* l) {
  __builtin_amdgcn_global_load_lds(
      (const __attribute__((address_space(1))) void*)g,
      (__attribute__((address_space(3))) void*)l, 16, 0, 0);
}

__device__ __forceinline__ float phi_act(float x) {
  return x > 0.f ? x + 1.f : __expf(x);
}

// ---------- elementwise f32 -> f16 ----------
__global__ void k_cvt(const float* __restrict__ src, _Float16* __restrict__ dst, int n4) {
  int stride = gridDim.x * blockDim.x;
  for (int i = blockIdx.x * blockDim.x + threadIdx.x; i < n4; i += stride) {
    float4 v = reinterpret_cast<const float4*>(src)[i];
    half4v h;
    h[0] = (_Float16)v.x; h[1] = (_Float16)v.y; h[2] = (_Float16)v.z; h[3] = (_Float16)v.w;
    reinterpret_cast<half4v*>(dst)[i] = h;
  }
}

// ---------- transpose+convert three 1024x1024 weights: W[f][n] -> WT16[n][f] ----------
__global__ void k_cvt_t(const float* __restrict__ W0, const float* __restrict__ W1,
                        const float* __restrict__ W2,
                        _Float16* __restrict__ T0, _Float16* __restrict__ T1,
                        _Float16* __restrict__ T2) {
  __shared__ float tile[32][33];
  int bid = blockIdx.x;
  int w = bid >> 10, rem = bid & 1023;
  int ti = rem >> 5, tj = rem & 31;
  const float* src = (w == 0) ? W0 : (w == 1) ? W1 : W2;
  _Float16*    dst = (w == 0) ? T0 : (w == 1) ? T1 : T2;
  int t = threadIdx.x;
  int r = t >> 3, c4 = (t & 7) << 2;
  float4 v = *reinterpret_cast<const float4*>(&src[(size_t)(ti * 32 + r) * FF + tj * 32 + c4]);
  tile[r][c4 + 0] = v.x; tile[r][c4 + 1] = v.y; tile[r][c4 + 2] = v.z; tile[r][c4 + 3] = v.w;
  __syncthreads();
  half4v h;
  h[0] = (_Float16)tile[c4 + 0][r];
  h[1] = (_Float16)tile[c4 + 1][r];
  h[2] = (_Float16)tile[c4 + 2][r];
  h[3] = (_Float16)tile[c4 + 3][r];
  *reinterpret_cast<half4v*>(&dst[(size_t)(tj * 32 + r) * FF + ti * 32 + c4]) = h;
}

// ============ 256x256-tile 8-phase GEMM (BK=64, 8 waves 2x4) ============
// A[M,1024] f16 row-major, BT[N(=1024),1024] f16 row-major.
// LDS planes (16KB each): A: [2 buf][2 kk][256 rows][32 k] at smem+0,
//                         B: same at smem+32768 elems. Total 128 KiB.
// Swizzle (involution): byte ^= ((byte>>7)&3)<<4.
// gload_lds dest stays LINEAR; global source is pre-swizzled; frag reads use khix.

__device__ __forceinline__ void stage_plane(const _Float16* __restrict__ G, int row0,
                                            int col0, _Float16* plane, int tid) {
  #pragma unroll
  for (int is = 0; is < 2; ++is) {
    int lin = is * 8192 + tid * 16;                    // byte offset in plane
    int swz = lin ^ (((lin >> 7) & 3) << 4);
    int row = swz >> 6, kcb = swz & 63;
    gload_lds16(G + (size_t)(row0 + row) * 1024 + col0 + (kcb >> 1),
                (char*)plane + lin);
  }
}

// Phase: stage 2 gloads -> pre-barrier ds_read frags -> [vmcnt(4) on even phases]
// -> s_barrier -> 16 MFMA.  Hazards: odd-phase reads of planes staged p-4/p-3
// are covered by even-phase vmcnt(4)+barrier at p-1 (executed by ALL waves);
// plane overwrites are >=2 barriers after last reader's lgkm completion.
template<int BUF, int KKH, int MH, bool LOADB, bool VM4>
__device__ __forceinline__ void do_phase(const _Float16* __restrict__ Gst, int srow0, int scol0,
                                         _Float16* splane, int tid,
                                         const _Float16* sm, floatx4 (&acc)[8][4],
                                         half8 (&bfr)[4], int wr, int wc, int lr, int khix) {
  stage_plane(Gst, srow0, scol0, splane, tid);
  const _Float16* pa = sm + (BUF * 2 + KKH) * 8192 + (wr * 128 + MH * 64 + lr) * 32 + khix * 8;
  const _Float16* pb = sm + 32768 + (BUF * 2 + KKH) * 8192 + (wc * 64 + lr) * 32 + khix * 8;
  half8 af[4];
  #pragma unroll
  for (int mm = 0; mm < 4; ++mm) af[mm] = *(const half8*)(pa + mm * 16 * 32);
  if constexpr (LOADB) {
    #pragma unroll
    for (int n = 0; n < 4; ++n) bfr[n] = *(const half8*)(pb + n * 16 * 32);
  }
  __builtin_amdgcn_sched_barrier(0);
  if constexpr (VM4) {
    asm volatile("s_waitcnt vmcnt(4)" ::: "memory");
    __builtin_amdgcn_sched_barrier(0);
  }
  __builtin_amdgcn_s_barrier();
  __builtin_amdgcn_sched_barrier(0);
  __builtin_amdgcn_s_setprio(1);
  #pragma unroll
  for (int mm = 0; mm < 4; ++mm)
    #pragma unroll
    for (int n = 0; n < 4; ++n)
      acc[MH * 4 + mm][n] =
          __builtin_amdgcn_mfma_f32_16x16x32_f16(af[mm], bfr[n], acc[MH * 4 + mm][n], 0, 0, 0);
  __builtin_amdgcn_s_setprio(0);
}

// MODE 0: f16 C[row*1024+col] (opt PHI)   MODE 1: f16 transposed CT[b][1024][8192]
// MODE 2: f32 C*outScale, BT indexed per-batch
template<int MODE, bool PHI>
__global__ __launch_bounds__(512, 2)
void k_gemm(const _Float16* __restrict__ A, const _Float16* __restrict__ BT,
            void* __restrict__ Cptr, float outScale) {
  __shared__ __align__(16) _Float16 smem[65536];   // 128 KiB
  const int tid  = threadIdx.x;
  const int lane = tid & 63;
  const int wid  = tid >> 6;
  const int wr = wid >> 2, wc = wid & 3;
  const int lr = lane & 15, lh = lane >> 4;
  const int khix = lh ^ ((lr >> 1) & 3);           // swizzled k-quad for frag reads

  // XCD-chunked block swizzle: 512 blocks, 64 contiguous tiles per XCD
  const int tile = (blockIdx.x & 7) * 64 + (blockIdx.x >> 3);
  const int tm = tile >> 2, tn = tile & 3;
  const int i0 = tm * 256, j0 = tn * 256;

  const _Float16* Ab = A;
  const _Float16* Bb = (MODE == 2) ? BT + ((size_t)(i0 >> 13)) * ((size_t)NN * KK) : BT;

  floatx4 acc[8][4];
  #pragma unroll
  for (int m = 0; m < 8; ++m)
    #pragma unroll
    for (int n = 0; n < 4; ++n)
      #pragma unroll
      for (int r = 0; r < 4; ++r) acc[m][n][r] = 0.f;

  _Float16* sm = (_Float16*)smem;
  // prologue: stage K-tile 0 (A-k0, B-k0, A-k1, B-k1) into buf0, drain, barrier
  stage_plane(Ab, i0, 0,  sm + 0,             tid);
  stage_plane(Bb, j0, 0,  sm + 32768,         tid);
  stage_plane(Ab, i0, 32, sm + 8192,          tid);
  stage_plane(Bb, j0, 32, sm + 32768 + 8192,  tid);
  asm volatile("s_waitcnt vmcnt(0)" ::: "memory");
  __builtin_amdgcn_sched_barrier(0);
  __builtin_amdgcn_s_barrier();
  __builtin_amdgcn_sched_barrier(0);

  half8 bfr[4];
  #pragma unroll 1
  for (int t2 = 0; t2 < 8; ++t2) {
    const int ka = ((t2 * 2 + 1) & 15) * 64;   // k-col of next tile
    const int kb = ((t2 * 2 + 2) & 15) * 64;   // k-col of tile after (wraps: dummy on last)
    // ---- tile t0 (buf0), stage next into buf1 ----
    do_phase<0,0,0,true ,false>(Ab, i0, ka +  0, sm + 16384,                tid, sm, acc, bfr, wr, wc, lr, khix);
    do_phase<0,0,1,false,true >(Bb, j0, ka +  0, sm + 32768 + 16384,        tid, sm, acc, bfr, wr, wc, lr, khix);
    do_phase<0,1,0,true ,false>(Ab, i0, ka + 32, sm + 16384 + 8192,         tid, sm, acc, bfr, wr, wc, lr, khix);
    do_phase<0,1,1,false,true >(Bb, j0, ka + 32, sm + 32768 + 16384 + 8192, tid, sm, acc, bfr, wr, wc, lr, khix);
    // ---- tile t1 (buf1), stage next into buf0 ----
    do_phase<1,0,0,true ,false>(Ab, i0, kb +  0, sm + 0,                    tid, sm, acc, bfr, wr, wc, lr, khix);
    do_phase<1,0,1,false,true >(Bb, j0, kb +  0, sm + 32768,                tid, sm, acc, bfr, wr, wc, lr, khix);
    do_phase<1,1,0,true ,false>(Ab, i0, kb + 32, sm + 8192,                 tid, sm, acc, bfr, wr, wc, lr, khix);
    do_phase<1,1,1,false,true >(Bb, j0, kb + 32, sm + 32768 + 8192,         tid, sm, acc, bfr, wr, wc, lr, khix);
  }

  asm volatile("s_waitcnt vmcnt(0)" ::: "memory");
  __builtin_amdgcn_sched_barrier(0);
  __builtin_amdgcn_s_barrier();

  if constexpr (MODE == 0) {
    _Float16* C = (_Float16*)Cptr;
    #pragma unroll
    for (int m = 0; m < 8; ++m) {
      int row = i0 + wr * 128 + m * 16 + lh * 4;
      #pragma unroll
      for (int n = 0; n < 4; ++n) {
        int col = j0 + wc * 64 + n * 16 + lr;
        #pragma unroll
        for (int r = 0; r < 4; ++r) {
          float v = acc[m][n][r];
          if constexpr (PHI) v = phi_act(v);
          C[(size_t)(row + r) * NN + col] = (_Float16)v;
        }
      }
    }
  } else if constexpr (MODE == 2) {
    float* C = (float*)Cptr;
    #pragma unroll
    for (int m = 0; m < 8; ++m) {
      int row = i0 + wr * 128 + m * 16 + lh * 4;
      #pragma unroll
      for (int n = 0; n < 4; ++n) {
        int col = j0 + wc * 64 + n * 16 + lr;
        #pragma unroll
        for (int r = 0; r < 4; ++r)
          C[(size_t)(row + r) * NN + col] = acc[m][n][r] * outScale;
      }
    }
  } else {
    // transposed store via LDS (reuse smem = 256n x 256l f16 = 128KB exactly)
    #pragma unroll
    for (int m = 0; m < 8; ++m) {
      int l0l = wr * 128 + m * 16 + lh * 4;
      #pragma unroll
      for (int n = 0; n < 4; ++n) {
        int n_loc = wc * 64 + n * 16 + lr;
        int byte = (n_loc * 512 + l0l * 2) ^ ((n_loc & 7) << 4);
        half4v h;
        #pragma unroll
        for (int r = 0; r < 4; ++r) {
          float v = acc[m][n][r];
          if constexpr (PHI) v = phi_act(v);
          h[r] = (_Float16)v;
        }
        *(half4v*)((char*)sm + byte) = h;
      }
    }
    __syncthreads();
    _Float16* C = (_Float16*)Cptr;
    const int bb = i0 >> 13;
    const int l0 = i0 & 8191;
    #pragma unroll 1
    for (int pass = 0; pass < 16; ++pass) {
      int n_loc = pass * 16 + (tid >> 5);
      int lo = (tid & 31) * 16;                     // byte offset within 512B l-row
      int byte = (n_loc * 512 + lo) ^ ((n_loc & 7) << 4);
      half8 v = *(const half8*)((char*)sm + byte);
      *(half8*)&C[((size_t)bb * 1024 + j0 + n_loc) * LL + l0 + (lo >> 1)] = v;
    }
  }
}

// ---------- ksum[b,h,d] = sum_l phi(k): row sums of kpT ----------
__global__ void k_ksum(const _Float16* __restrict__ kpT, float* __restrict__ ksum) {
  int w = threadIdx.x >> 6, lane = threadIdx.x & 63;
  int row = blockIdx.x * 4 + w;
  const _Float16* p = kpT + (size_t)row * LL;
  float s = 0.f;
  for (int j = 0; j < 16; ++j) {
    half8 v = *(const half8*)&p[j * 512 + lane * 8];
    #pragma unroll
    for (int e = 0; e < 8; ++e) s += (float)v[e];
  }
  #pragma unroll
  for (int off = 1; off < 64; off <<= 1) s += __shfl_xor(s, off);
  if (lane == 0) ksum[row] = s;
}

// ---------- kv partials: per (b,h,chunk) wave computes 64x64 = kp^T(chunk) * v(chunk) ----------
__global__ __launch_bounds__(64)
void k_stageB(const _Float16* __restrict__ kpT, const _Float16* __restrict__ vT,
              float* __restrict__ kvpart) {
  __shared__ _Float16 Ak[64 * 72];
  __shared__ _Float16 Bv[64 * 72];
  const int bid = blockIdx.x;
  const int bh = bid >> 4, cc = bid & 15;
  const int lane = threadIdx.x;
  const int lr = lane & 15, lh = lane >> 4;
  const _Float16* Ab = kpT + (size_t)bh * 64 * LL + cc * 512;
  const _Float16* Bb = vT  + (size_t)bh * 64 * LL + cc * 512;

  floatx4 acc[4][4];
  #pragma unroll
  for (int m = 0; m < 4; ++m)
    #pragma unroll
    for (int n = 0; n < 4; ++n)
      #pragma unroll
      for (int r = 0; r < 4; ++r) acc[m][n][r] = 0.f;

  for (int kt = 0; kt < 512; kt += 64) {
    __syncthreads();
    #pragma unroll
    for (int j = 0; j < 8; ++j) {
      int chunk = lane + 64 * j;
      int rr = chunk >> 3;
      int off = (chunk & 7) * 8;
      *(half8*)&Ak[rr * 72 + off] = *(const half8*)&Ab[(size_t)rr * LL + kt + off];
      *(half8*)&Bv[rr * 72 + off] = *(const half8*)&Bb[(size_t)rr * LL + kt + off];
    }
    __syncthreads();
    #pragma unroll
    for (int ks = 0; ks < 2; ++ks) {
      half8 af[4], bf[4];
      #pragma unroll
      for (int m = 0; m < 4; ++m) af[m] = *(const half8*)&Ak[(m * 16 + lr) * 72 + ks * 32 + lh * 8];
      #pragma unroll
      for (int n = 0; n < 4; ++n) bf[n] = *(const half8*)&Bv[(n * 16 + lr) * 72 + ks * 32 + lh * 8];
      #pragma unroll
      for (int m = 0; m < 4; ++m)
        #pragma unroll
        for (int n = 0; n < 4; ++n)
          acc[m][n] = __builtin_amdgcn_mfma_f32_16x16x32_f16(af[m], bf[n], acc[m][n], 0, 0, 0);
    }
  }
  float* op = kvpart + (size_t)bid * 4096;
  #pragma unroll
  for (int m = 0; m < 4; ++m)
    #pragma unroll
    for (int n = 0; n < 4; ++n)
      #pragma unroll
      for (int r = 0; r < 4; ++r)
        op[(m * 16 + lh * 4 + r) * 64 + n * 16 + lr] = acc[m][n][r];
}

// ---------- reduce kv partials over 16 chunks ----------
__global__ void k_reduce_kv(const float* __restrict__ kvpart, float* __restrict__ kv) {
  int gid = blockIdx.x * 256 + threadIdx.x;
  int bh = gid >> 12, i = gid & 4095;
  float s = 0.f;
  for (int c = 0; c < 16; ++c) s += kvpart[((size_t)bh * 16 + c) * 4096 + i];
  kv[gid] = s;
}

// ---------- z = ZSCALE / (phi(q).ksum + eps); qp *= z in place ----------
__global__ void k_zscale(_Float16* __restrict__ qp, const float* __restrict__ ksum) {
  int w = threadIdx.x >> 6, lane = threadIdx.x & 63;
  int row = blockIdx.x * 4 + w;
  int b = row >> 13;
  int h = lane >> 2;
  _Float16* p = qp + (size_t)row * 1024 + lane * 16;
  half8 v0 = *(half8*)&p[0];
  half8 v1 = *(half8*)&p[8];
  const float* ks = ksum + ((size_t)b * 16 + h) * 64 + (lane & 3) * 16;
  float dot = 0.f;
  #pragma unroll
  for (int e = 0; e < 8; ++e) dot += (float)v0[e] * ks[e];
  #pragma unroll
  for (int e = 0; e < 8; ++e) dot += (float)v1[e] * ks[8 + e];
  dot += __shfl_xor(dot, 1);
  dot += __shfl_xor(dot, 2);
  float zf = ZSCALE / (dot + 1e-6f);
  #pragma unroll
  for (int e = 0; e < 8; ++e) v0[e] = (_Float16)((float)v0[e] * zf);
  #pragma unroll
  for (int e = 0; e < 8; ++e) v1[e] = (_Float16)((float)v1[e] * zf);
  *(half8*)&p[0] = v0;
  *(half8*)&p[8] = v1;
}

// ---------- MT[b][f][h*64+d] = sum_e kv[b,h,d,e] * Wo[h,e,f] ----------
__global__ __launch_bounds__(256)
void k_mker(const float* __restrict__ kv, const _Float16* __restrict__ Wo16,
            _Float16* __restrict__ MT) {
  __shared__ float kvs[4096];
  int bid = blockIdx.x;
  int fc = bid & 3, h = (bid >> 2) & 15, b = bid >> 6;
  const float* kvp = kv + ((size_t)b * 16 + h) * 4096;
  for (int i = threadIdx.x; i < 4096; i += 256) kvs[i] = kvp[i];
  __syncthreads();
  int f = fc * 256 + threadIdx.x;
  float acc[64];
  #pragma unroll
  for (int d = 0; d < 64; ++d) acc[d] = 0.f;
  for (int e = 0; e < 64; ++e) {
    float wv = (float)Wo16[(size_t)(h * 64 + e) * 1024 + f];
    #pragma unroll
    for (int d = 0; d < 64; ++d) acc[d] = fmaf(kvs[d * 64 + e], wv, acc[d]);
  }
  _Float16* op = MT + ((size_t)b * 1024 + f) * 1024 + h * 64;
  #pragma unroll
  for (int g = 0; g < 8; ++g) {
    half8 o;
    #pragma unroll
    for (int j = 0; j < 8; ++j) o[j] = (_Float16)acc[g * 8 + j];
    *(half8*)&op[g * 8] = o;
  }
}

extern "C" void kernel_launch(void* const* d_in, const int* in_sizes, int n_in,
                              void* d_out, int out_size, void* d_ws, size_t ws_size,
                              hipStream_t stream) {
  (void)in_sizes; (void)n_in; (void)out_size; (void)ws_size;
  const float* xq  = (const float*)d_in[0];
  const float* xkv = (const float*)d_in[1];
  const float* Wq  = (const float*)d_in[2];
  const float* Wk  = (const float*)d_in[3];
  const float* Wv  = (const float*)d_in[4];
  const float* Wo  = (const float*)d_in[5];

  char* ws = (char*)d_ws;
  _Float16* qp16 = (_Float16*)(ws + 0);           // [32768][1024]
  _Float16* kpT  = (_Float16*)(ws + 67108864);    // [4][1024][8192]
  _Float16* vT   = (_Float16*)(ws + 134217728);   // [4][1024][8192]
  _Float16* WqT  = (_Float16*)(ws + 201326592);
  _Float16* WkT  = (_Float16*)(ws + 203423744);
  _Float16* WvT  = (_Float16*)(ws + 205520896);
  _Float16* Wo16 = (_Float16*)(ws + 207618048);
  float*    ksum = (float*)(ws + 209715200);
  float*    kv   = (float*)(ws + 209731584);
  float*    kvpart = (float*)(ws + 210780160);
  _Float16* MT   = (_Float16*)(ws + 227557376);   // [4][1024][1024]

  _Float16* Xq16  = (_Float16*)d_out;
  _Float16* Xkv16 = Xq16 + 33554432;

  k_cvt<<<2048, 256, 0, stream>>>(xq,  Xq16,  8388608);
  k_cvt<<<2048, 256, 0, stream>>>(xkv, Xkv16, 8388608);
  k_cvt<<<512,  256, 0, stream>>>(Wo,  Wo16,  262144);
  k_cvt_t<<<3072, 256, 0, stream>>>(Wq, Wk, Wv, WqT, WkT, WvT);

  // projections: 256x256 tiles -> 128 x 4 = 512 blocks of 512 threads
  k_gemm<0, true ><<<512, 512, 0, stream>>>(Xq16,  WqT, qp16, 1.0f);
  k_gemm<1, true ><<<512, 512, 0, stream>>>(Xkv16, WkT, kpT,  1.0f);
  k_gemm<1, false><<<512, 512, 0, stream>>>(Xkv16, WvT, vT,   1.0f);

  k_ksum<<<1024, 256, 0, stream>>>(kpT, ksum);
  k_stageB<<<1024, 64, 0, stream>>>(kpT, vT, kvpart);
  k_reduce_kv<<<1024, 256, 0, stream>>>(kvpart, kv);

  k_zscale<<<8192, 256, 0, stream>>>(qp16, ksum);

  k_mker<<<256, 256, 0, stream>>>(kv, Wo16, MT);
  k_gemm<2, false><<<512, 512, 0, stream>>>(qp16, MT, d_out, 1.0f / ZSCALE);
}

// Round 5
// 512.553 us; speedup vs baseline: 1.2215x; 1.0008x over previous
//
#include <hip/hip_runtime.h>
#include <hip/hip_fp16.h>
#include <math.h>

typedef _Float16 half8  __attribute__((ext_vector_type(8)));
typedef _Float16 half4v __attribute__((ext_vector_type(4)));
typedef float    floatx4 __attribute__((ext_vector_type(4)));

#define NB   4
#define LL   8192
#define FF   1024
#define HH   16
#define DD   64
#define MTOT 32768
#define KK   1024
#define NN   1024
#define ZSCALE 65536.0f

__device__ __forceinline__ void gload_lds16(const void* g, void* l) {
  __builtin_amdgcn_global_load_lds(
      (const __attribute__((address_space(1))) void*)g,
      (__attribute__((address_space(3))) void*)l, 16, 0, 0);
}

__device__ __forceinline__ float phi_act(float x) {
  return x > 0.f ? x + 1.f : __expf(x);
}

// ---------- elementwise f32 -> f16 ----------
__global__ void k_cvt(const float* __restrict__ src, _Float16* __restrict__ dst, int n4) {
  int stride = gridDim.x * blockDim.x;
  for (int i = blockIdx.x * blockDim.x + threadIdx.x; i < n4; i += stride) {
    float4 v = reinterpret_cast<const float4*>(src)[i];
    half4v h;
    h[0] = (_Float16)v.x; h[1] = (_Float16)v.y; h[2] = (_Float16)v.z; h[3] = (_Float16)v.w;
    reinterpret_cast<half4v*>(dst)[i] = h;
  }
}

// ---------- transpose+convert three 1024x1024 weights: W[f][n] -> WT16[n][f] ----------
__global__ void k_cvt_t(const float* __restrict__ W0, const float* __restrict__ W1,
                        const float* __restrict__ W2,
                        _Float16* __restrict__ T0, _Float16* __restrict__ T1,
                        _Float16* __restrict__ T2) {
  __shared__ float tile[32][33];
  int bid = blockIdx.x;
  int w = bid >> 10, rem = bid & 1023;
  int ti = rem >> 5, tj = rem & 31;
  const float* src = (w == 0) ? W0 : (w == 1) ? W1 : W2;
  _Float16*    dst = (w == 0) ? T0 : (w == 1) ? T1 : T2;
  int t = threadIdx.x;
  int r = t >> 3, c4 = (t & 7) << 2;
  float4 v = *reinterpret_cast<const float4*>(&src[(size_t)(ti * 32 + r) * FF + tj * 32 + c4]);
  tile[r][c4 + 0] = v.x; tile[r][c4 + 1] = v.y; tile[r][c4 + 2] = v.z; tile[r][c4 + 3] = v.w;
  __syncthreads();
  half4v h;
  h[0] = (_Float16)tile[c4 + 0][r];
  h[1] = (_Float16)tile[c4 + 1][r];
  h[2] = (_Float16)tile[c4 + 2][r];
  h[3] = (_Float16)tile[c4 + 3][r];
  *reinterpret_cast<half4v*>(&dst[(size_t)(tj * 32 + r) * FF + ti * 32 + c4]) = h;
}

// ============ 256x256-tile 8-phase GEMM (BK=64, 8 waves 2x4) ============
// A[M,1024] f16 row-major, BT[N(=1024),1024] f16 row-major.
// LDS planes (16KB each): A: [2 buf][2 kk][256 rows][32 k] at smem+0,
//                         B: same at smem+32768 elems. Total 128 KiB.
// Swizzle (involution): byte ^= ((byte>>7)&3)<<4.
// gload_lds dest stays LINEAR; global source is pre-swizzled; frag reads use khix.
// NOTE r5: NO sched_barrier(0) pins — m141 evidence: order-pinning defeats the
// compiler scheduler. Ordering that matters (gload -> vmcnt -> s_barrier) is
// maintained by the "memory" clobber + side-effecting barrier intrinsic.

__device__ __forceinline__ void stage_plane(const _Float16* __restrict__ G, int row0,
                                            int col0, _Float16* plane, int tid) {
  #pragma unroll
  for (int is = 0; is < 2; ++is) {
    int lin = is * 8192 + tid * 16;                    // byte offset in plane
    int swz = lin ^ (((lin >> 7) & 3) << 4);
    int row = swz >> 6, kcb = swz & 63;
    gload_lds16(G + (size_t)(row0 + row) * 1024 + col0 + (kcb >> 1),
                (char*)plane + lin);
  }
}

// Phase: stage 2 gloads -> ds_read frags -> [vmcnt(4) on odd phases] -> s_barrier
// -> 16 MFMA (compiler inserts fine-grained lgkm waits on the data deps).
template<int BUF, int KKH, int MH, bool LOADB, bool VM4>
__device__ __forceinline__ void do_phase(const _Float16* __restrict__ Gst, int srow0, int scol0,
                                         _Float16* splane, int tid,
                                         const _Float16* sm, floatx4 (&acc)[8][4],
                                         half8 (&bfr)[4], int wr, int wc, int lr, int khix) {
  stage_plane(Gst, srow0, scol0, splane, tid);
  const _Float16* pa = sm + (BUF * 2 + KKH) * 8192 + (wr * 128 + MH * 64 + lr) * 32 + khix * 8;
  const _Float16* pb = sm + 32768 + (BUF * 2 + KKH) * 8192 + (wc * 64 + lr) * 32 + khix * 8;
  half8 af[4];
  #pragma unroll
  for (int mm = 0; mm < 4; ++mm) af[mm] = *(const half8*)(pa + mm * 16 * 32);
  if constexpr (LOADB) {
    #pragma unroll
    for (int n = 0; n < 4; ++n) bfr[n] = *(const half8*)(pb + n * 16 * 32);
  }
  if constexpr (VM4) {
    asm volatile("s_waitcnt vmcnt(4)" ::: "memory");
  }
  __builtin_amdgcn_s_barrier();
  __builtin_amdgcn_s_setprio(1);
  #pragma unroll
  for (int mm = 0; mm < 4; ++mm)
    #pragma unroll
    for (int n = 0; n < 4; ++n)
      acc[MH * 4 + mm][n] =
          __builtin_amdgcn_mfma_f32_16x16x32_f16(af[mm], bfr[n], acc[MH * 4 + mm][n], 0, 0, 0);
  __builtin_amdgcn_s_setprio(0);
}

// MODE 0: f16 C[row*1024+col] (opt PHI)   MODE 1: f16 transposed CT[b][1024][8192]
// MODE 2: f32 C*outScale, BT indexed per-batch
template<int MODE, bool PHI>
__global__ __launch_bounds__(512, 2)
void k_gemm(const _Float16* __restrict__ A, const _Float16* __restrict__ BT,
            void* __restrict__ Cptr, float outScale) {
  __shared__ __align__(16) _Float16 smem[65536];   // 128 KiB
  const int tid  = threadIdx.x;
  const int lane = tid & 63;
  const int wid  = tid >> 6;
  const int wr = wid >> 2, wc = wid & 3;
  const int lr = lane & 15, lh = lane >> 4;
  const int khix = lh ^ ((lr >> 1) & 3);           // swizzled k-quad for frag reads

  // XCD-chunked block swizzle: 512 blocks, 64 contiguous tiles per XCD
  const int tile = (blockIdx.x & 7) * 64 + (blockIdx.x >> 3);
  const int tm = tile >> 2, tn = tile & 3;
  const int i0 = tm * 256, j0 = tn * 256;

  const _Float16* Ab = A;
  const _Float16* Bb = (MODE == 2) ? BT + ((size_t)(i0 >> 13)) * ((size_t)NN * KK) : BT;

  floatx4 acc[8][4];
  #pragma unroll
  for (int m = 0; m < 8; ++m)
    #pragma unroll
    for (int n = 0; n < 4; ++n)
      #pragma unroll
      for (int r = 0; r < 4; ++r) acc[m][n][r] = 0.f;

  _Float16* sm = (_Float16*)smem;
  // prologue: stage K-tile 0 (A-k0, B-k0, A-k1, B-k1) into buf0, drain, barrier
  stage_plane(Ab, i0, 0,  sm + 0,             tid);
  stage_plane(Bb, j0, 0,  sm + 32768,         tid);
  stage_plane(Ab, i0, 32, sm + 8192,          tid);
  stage_plane(Bb, j0, 32, sm + 32768 + 8192,  tid);
  asm volatile("s_waitcnt vmcnt(0)" ::: "memory");
  __builtin_amdgcn_s_barrier();

  half8 bfr[4];
  #pragma unroll 1
  for (int t2 = 0; t2 < 8; ++t2) {
    const int ka = ((t2 * 2 + 1) & 15) * 64;   // k-col of next tile
    const int kb = ((t2 * 2 + 2) & 15) * 64;   // k-col of tile after (wraps: dummy on last)
    // ---- tile t0 (buf0), stage next into buf1 ----
    do_phase<0,0,0,true ,false>(Ab, i0, ka +  0, sm + 16384,                tid, sm, acc, bfr, wr, wc, lr, khix);
    do_phase<0,0,1,false,true >(Bb, j0, ka +  0, sm + 32768 + 16384,        tid, sm, acc, bfr, wr, wc, lr, khix);
    do_phase<0,1,0,true ,false>(Ab, i0, ka + 32, sm + 16384 + 8192,         tid, sm, acc, bfr, wr, wc, lr, khix);
    do_phase<0,1,1,false,true >(Bb, j0, ka + 32, sm + 32768 + 16384 + 8192, tid, sm, acc, bfr, wr, wc, lr, khix);
    // ---- tile t1 (buf1), stage next into buf0 ----
    do_phase<1,0,0,true ,false>(Ab, i0, kb +  0, sm + 0,                    tid, sm, acc, bfr, wr, wc, lr, khix);
    do_phase<1,0,1,false,true >(Bb, j0, kb +  0, sm + 32768,                tid, sm, acc, bfr, wr, wc, lr, khix);
    do_phase<1,1,0,true ,false>(Ab, i0, kb + 32, sm + 8192,                 tid, sm, acc, bfr, wr, wc, lr, khix);
    do_phase<1,1,1,false,true >(Bb, j0, kb + 32, sm + 32768 + 8192,         tid, sm, acc, bfr, wr, wc, lr, khix);
  }

  asm volatile("s_waitcnt vmcnt(0)" ::: "memory");
  __builtin_amdgcn_s_barrier();

  if constexpr (MODE == 0) {
    _Float16* C = (_Float16*)Cptr;
    #pragma unroll
    for (int m = 0; m < 8; ++m) {
      int row = i0 + wr * 128 + m * 16 + lh * 4;
      #pragma unroll
      for (int n = 0; n < 4; ++n) {
        int col = j0 + wc * 64 + n * 16 + lr;
        #pragma unroll
        for (int r = 0; r < 4; ++r) {
          float v = acc[m][n][r];
          if constexpr (PHI) v = phi_act(v);
          C[(size_t)(row + r) * NN + col] = (_Float16)v;
        }
      }
    }
  } else if constexpr (MODE == 2) {
    float* C = (float*)Cptr;
    #pragma unroll
    for (int m = 0; m < 8; ++m) {
      int row = i0 + wr * 128 + m * 16 + lh * 4;
      #pragma unroll
      for (int n = 0; n < 4; ++n) {
        int col = j0 + wc * 64 + n * 16 + lr;
        #pragma unroll
        for (int r = 0; r < 4; ++r)
          C[(size_t)(row + r) * NN + col] = acc[m][n][r] * outScale;
      }
    }
  } else {
    // transposed store via LDS (reuse smem = 256n x 256l f16 = 128KB exactly)
    #pragma unroll
    for (int m = 0; m < 8; ++m) {
      int l0l = wr * 128 + m * 16 + lh * 4;
      #pragma unroll
      for (int n = 0; n < 4; ++n) {
        int n_loc = wc * 64 + n * 16 + lr;
        int byte = (n_loc * 512 + l0l * 2) ^ ((n_loc & 7) << 4);
        half4v h;
        #pragma unroll
        for (int r = 0; r < 4; ++r) {
          float v = acc[m][n][r];
          if constexpr (PHI) v = phi_act(v);
          h[r] = (_Float16)v;
        }
        *(half4v*)((char*)sm + byte) = h;
      }
    }
    __syncthreads();
    _Float16* C = (_Float16*)Cptr;
    const int bb = i0 >> 13;
    const int l0 = i0 & 8191;
    #pragma unroll 1
    for (int pass = 0; pass < 16; ++pass) {
      int n_loc = pass * 16 + (tid >> 5);
      int lo = (tid & 31) * 16;                     // byte offset within 512B l-row
      int byte = (n_loc * 512 + lo) ^ ((n_loc & 7) << 4);
      half8 v = *(const half8*)((char*)sm + byte);
      *(half8*)&C[((size_t)bb * 1024 + j0 + n_loc) * LL + l0 + (lo >> 1)] = v;
    }
  }
}

// ---------- ksum[b,h,d] = sum_l phi(k): row sums of kpT ----------
__global__ void k_ksum(const _Float16* __restrict__ kpT, float* __restrict__ ksum) {
  int w = threadIdx.x >> 6, lane = threadIdx.x & 63;
  int row = blockIdx.x * 4 + w;
  const _Float16* p = kpT + (size_t)row * LL;
  float s = 0.f;
  for (int j = 0; j < 16; ++j) {
    half8 v = *(const half8*)&p[j * 512 + lane * 8];
    #pragma unroll
    for (int e = 0; e < 8; ++e) s += (float)v[e];
  }
  #pragma unroll
  for (int off = 1; off < 64; off <<= 1) s += __shfl_xor(s, off);
  if (lane == 0) ksum[row] = s;
}

// ---------- kv partials: per (b,h,chunk) wave computes 64x64 = kp^T(chunk) * v(chunk) ----------
__global__ __launch_bounds__(64)
void k_stageB(const _Float16* __restrict__ kpT, const _Float16* __restrict__ vT,
              float* __restrict__ kvpart) {
  __shared__ _Float16 Ak[64 * 72];
  __shared__ _Float16 Bv[64 * 72];
  const int bid = blockIdx.x;
  const int bh = bid >> 4, cc = bid & 15;
  const int lane = threadIdx.x;
  const int lr = lane & 15, lh = lane >> 4;
  const _Float16* Ab = kpT + (size_t)bh * 64 * LL + cc * 512;
  const _Float16* Bb = vT  + (size_t)bh * 64 * LL + cc * 512;

  floatx4 acc[4][4];
  #pragma unroll
  for (int m = 0; m < 4; ++m)
    #pragma unroll
    for (int n = 0; n < 4; ++n)
      #pragma unroll
      for (int r = 0; r < 4; ++r) acc[m][n][r] = 0.f;

  for (int kt = 0; kt < 512; kt += 64) {
    __syncthreads();
    #pragma unroll
    for (int j = 0; j < 8; ++j) {
      int chunk = lane + 64 * j;
      int rr = chunk >> 3;
      int off = (chunk & 7) * 8;
      *(half8*)&Ak[rr * 72 + off] = *(const half8*)&Ab[(size_t)rr * LL + kt + off];
      *(half8*)&Bv[rr * 72 + off] = *(const half8*)&Bb[(size_t)rr * LL + kt + off];
    }
    __syncthreads();
    #pragma unroll
    for (int ks = 0; ks < 2; ++ks) {
      half8 af[4], bf[4];
      #pragma unroll
      for (int m = 0; m < 4; ++m) af[m] = *(const half8*)&Ak[(m * 16 + lr) * 72 + ks * 32 + lh * 8];
      #pragma unroll
      for (int n = 0; n < 4; ++n) bf[n] = *(const half8*)&Bv[(n * 16 + lr) * 72 + ks * 32 + lh * 8];
      #pragma unroll
      for (int m = 0; m < 4; ++m)
        #pragma unroll
        for (int n = 0; n < 4; ++n)
          acc[m][n] = __builtin_amdgcn_mfma_f32_16x16x32_f16(af[m], bf[n], acc[m][n], 0, 0, 0);
    }
  }
  float* op = kvpart + (size_t)bid * 4096;
  #pragma unroll
  for (int m = 0; m < 4; ++m)
    #pragma unroll
    for (int n = 0; n < 4; ++n)
      #pragma unroll
      for (int r = 0; r < 4; ++r)
        op[(m * 16 + lh * 4 + r) * 64 + n * 16 + lr] = acc[m][n][r];
}

// ---------- reduce kv partials over 16 chunks ----------
__global__ void k_reduce_kv(const float* __restrict__ kvpart, float* __restrict__ kv) {
  int gid = blockIdx.x * 256 + threadIdx.x;
  int bh = gid >> 12, i = gid & 4095;
  float s = 0.f;
  for (int c = 0; c < 16; ++c) s += kvpart[((size_t)bh * 16 + c) * 4096 + i];
  kv[gid] = s;
}

// ---------- z = ZSCALE / (phi(q).ksum + eps); qp *= z in place ----------
__global__ void k_zscale(_Float16* __restrict__ qp, const float* __restrict__ ksum) {
  int w = threadIdx.x >> 6, lane = threadIdx.x & 63;
  int row = blockIdx.x * 4 + w;
  int b = row >> 13;
  int h = lane >> 2;
  _Float16* p = qp + (size_t)row * 1024 + lane * 16;
  half8 v0 = *(half8*)&p[0];
  half8 v1 = *(half8*)&p[8];
  const float* ks = ksum + ((size_t)b * 16 + h) * 64 + (lane & 3) * 16;
  float dot = 0.f;
  #pragma unroll
  for (int e = 0; e < 8; ++e) dot += (float)v0[e] * ks[e];
  #pragma unroll
  for (int e = 0; e < 8; ++e) dot += (float)v1[e] * ks[8 + e];
  dot += __shfl_xor(dot, 1);
  dot += __shfl_xor(dot, 2);
  float zf = ZSCALE / (dot + 1e-6f);
  #pragma unroll
  for (int e = 0; e < 8; ++e) v0[e] = (_Float16)((float)v0[e] * zf);
  #pragma unroll
  for (int e = 0; e < 8; ++e) v1[e] = (_Float16)((float)v1[e] * zf);
  *(half8*)&p[0] = v0;
  *(half8*)&p[8] = v1;
}

// ---------- MT[b][f][h*64+d] = sum_e kv[b,h,d,e] * Wo[h,e,f] ----------
__global__ __launch_bounds__(256)
void k_mker(const float* __restrict__ kv, const _Float16* __restrict__ Wo16,
            _Float16* __restrict__ MT) {
  __shared__ float kvs[4096];
  int bid = blockIdx.x;
  int fc = bid & 3, h = (bid >> 2) & 15, b = bid >> 6;
  const float* kvp = kv + ((size_t)b * 16 + h) * 4096;
  for (int i = threadIdx.x; i < 4096; i += 256) kvs[i] = kvp[i];
  __syncthreads();
  int f = fc * 256 + threadIdx.x;
  float acc[64];
  #pragma unroll
  for (int d = 0; d < 64; ++d) acc[d] = 0.f;
  for (int e = 0; e < 64; ++e) {
    float wv = (float)Wo16[(size_t)(h * 64 + e) * 1024 + f];
    #pragma unroll
    for (int d = 0; d < 64; ++d) acc[d] = fmaf(kvs[d * 64 + e], wv, acc[d]);
  }
  _Float16* op = MT + ((size_t)b * 1024 + f) * 1024 + h * 64;
  #pragma unroll
  for (int g = 0; g < 8; ++g) {
    half8 o;
    #pragma unroll
    for (int j = 0; j < 8; ++j) o[j] = (_Float16)acc[g * 8 + j];
    *(half8*)&op[g * 8] = o;
  }
}

extern "C" void kernel_launch(void* const* d_in, const int* in_sizes, int n_in,
                              void* d_out, int out_size, void* d_ws, size_t ws_size,
                              hipStream_t stream) {
  (void)in_sizes; (void)n_in; (void)out_size; (void)ws_size;
  const float* xq  = (const float*)d_in[0];
  const float* xkv = (const float*)d_in[1];
  const float* Wq  = (const float*)d_in[2];
  const float* Wk  = (const float*)d_in[3];
  const float* Wv  = (const float*)d_in[4];
  const float* Wo  = (const float*)d_in[5];

  char* ws = (char*)d_ws;
  _Float16* qp16 = (_Float16*)(ws + 0);           // [32768][1024]
  _Float16* kpT  = (_Float16*)(ws + 67108864);    // [4][1024][8192]
  _Float16* vT   = (_Float16*)(ws + 134217728);   // [4][1024][8192]
  _Float16* WqT  = (_Float16*)(ws + 201326592);
  _Float16* WkT  = (_Float16*)(ws + 203423744);
  _Float16* WvT  = (_Float16*)(ws + 205520896);
  _Float16* Wo16 = (_Float16*)(ws + 207618048);
  float*    ksum = (float*)(ws + 209715200);
  float*    kv   = (float*)(ws + 209731584);
  float*    kvpart = (float*)(ws + 210780160);
  _Float16* MT   = (_Float16*)(ws + 227557376);   // [4][1024][1024]

  _Float16* Xq16  = (_Float16*)d_out;
  _Float16* Xkv16 = Xq16 + 33554432;

  k_cvt<<<2048, 256, 0, stream>>>(xq,  Xq16,  8388608);
  k_cvt<<<2048, 256, 0, stream>>>(xkv, Xkv16, 8388608);
  k_cvt<<<512,  256, 0, stream>>>(Wo,  Wo16,  262144);
  k_cvt_t<<<3072, 256, 0, stream>>>(Wq, Wk, Wv, WqT, WkT, WvT);

  // projections: 256x256 tiles -> 128 x 4 = 512 blocks of 512 threads
  k_gemm<0, true ><<<512, 512, 0, stream>>>(Xq16,  WqT, qp16, 1.0f);
  k_gemm<1, true ><<<512, 512, 0, stream>>>(Xkv16, WkT, kpT,  1.0f);
  k_gemm<1, false><<<512, 512, 0, stream>>>(Xkv16, WvT, vT,   1.0f);

  k_ksum<<<1024, 256, 0, stream>>>(kpT, ksum);
  k_stageB<<<1024, 64, 0, stream>>>(kpT, vT, kvpart);
  k_reduce_kv<<<1024, 256, 0, stream>>>(kvpart, kv);

  k_zscale<<<8192, 256, 0, stream>>>(qp16, ksum);

  k_mker<<<256, 256, 0, stream>>>(kv, Wo16, MT);
  k_gemm<2, false><<<512, 512, 0, stream>>>(qp16, MT, d_out, 1.0f / ZSCALE);
}